// Round 14
// baseline (222.372 us; speedup 1.0000x reference)
//
#include <hip/hip_runtime.h>
#include <cfloat>
#include <cmath>

#define NP 10000
#define NG 1000
#define NC 80
#define LMAX 6
#define NCH 2
#define CHSZ (NP / NCH)
#define MAIN_IT 19          // 19*256 = 4864 uniform indices per 5000-chunk
#define TAIL_N  136         // remaining 136 indices

#define S_MULTI 12
#define S_BODY  16
#define RI_BIG  0x3fffffff
#define KMAX    0xFFFFFFFFFFFFFFFFull

__device__ __forceinline__ bool lexless(float av, int ai, float bv, int bi) {
    return (av < bv) || (av == bv && ai < bi);
}

// float -> order-preserving u32 (no NaNs in this data), packed with index.
// ascending u64 order == lexicographic (value asc, index asc).
__device__ __forceinline__ unsigned long long packkey(float v, int idx) {
    unsigned u = __float_as_uint(v);
    u ^= (unsigned)(((int)u) >> 31) | 0x80000000u;
    return ((unsigned long long)u << 32) | (unsigned)idx;
}
__device__ __forceinline__ int keyidx(unsigned long long k) {
    return (int)(unsigned)(k & 0xFFFFFFFFu);
}
__device__ __forceinline__ float keyval(unsigned long long k) {
    unsigned u = (unsigned)(k >> 32);
    u = (u & 0x80000000u) ? (u ^ 0x80000000u) : ~u;   // inverse transform
    return __uint_as_float(u);
}

// Exact sequential +1e5 inflation (reference adds 1e5 once per loop iter).
__device__ __forceinline__ float inflate(float c, int k) {
    for (int q = 0; q < k; q++) c += 100000.0f;
    return c;
}

// Per-pair cost+iou from precomputed tables. Contraction OFF so every kernel
// that recomputes cost(i,j) agrees bit-exactly.
__device__ __forceinline__ void cost_iou(float4 p, float4 pn, float4 pi,
        float4 g, float4 cb, float4 Gn, float ga, float clsv,
        float& cc_out, float& iou_out) {
#pragma clang fp contract(off)
    float wx = fminf(p.z, g.z) - fmaxf(p.x, g.x); wx = fmaxf(wx, 0.0f);
    float wy = fminf(p.w, g.w) - fmaxf(p.y, g.y); wy = fmaxf(wy, 0.0f);
    float inter = wx * wy;
    float uni = pi.z + ga - inter;
    float iou = inter / fmaxf(uni, 1e-12f);
    float ex = fmaxf(p.z, g.z) - fminf(p.x, g.x); ex = fmaxf(ex, 0.0f);
    float ey = fmaxf(p.w, g.w) - fminf(p.y, g.y); ey = fmaxf(ey, 0.0f);
    float enc = ex * ey;
    float giou = iou - (enc - uni) / fmaxf(enc, 1e-12f);
    float l1 = ((fabsf(pn.x - Gn.x) + fabsf(pn.y - Gn.y))
                + fabsf(pn.z - Gn.z)) + fabsf(pn.w - Gn.w);
    float cc = clsv + l1 * 5.0f;
    cc = cc + (-giou * 2.0f);
    bool inb = (pi.x > g.x && pi.x < g.z && pi.y > g.y && pi.y < g.w);
    bool inc = (pi.x > cb.x && pi.x < cb.z && pi.y > cb.y && pi.y < cb.w);
    cc = cc + ((inb && inc) ? 0.0f : 100.0f);
    cc = cc + pi.w;
    cc_out = cc; iou_out = iou;
}

// ---------------------------------------------------------------------------
// Fused prep. Block ranges:
//  [0,40): init state; [40,197): cls table; [197,201): per-gt tables;
//  [201,2701): wave-per-pred validity + per-pred tables
// ---------------------------------------------------------------------------
#define CLS_TI 64
#define PB_CLS0 40
#define PB_G0   197
#define PB_V0   201
__global__ __launch_bounds__(256) void k_prep(const float* __restrict__ logits,
        const float* __restrict__ pb, const float* __restrict__ gb,
        const int* __restrict__ imgw, const int* __restrict__ imgh,
        float* __restrict__ clsval, float4* __restrict__ pnorm,
        float4* __restrict__ pinfo, float4* __restrict__ gcb,
        float4* __restrict__ gnm, float* __restrict__ gar,
        int* rowcnt, int* rowfirst, int* rowiter, int* prior, int* priorcol,
        int* colsum, int* scal, int* done)
{
    __shared__ float sl[CLS_TI * (NC + 1)];
    int b = blockIdx.x;
    if (b < PB_CLS0) {
        int i = b * 256 + threadIdx.x;
        if (i < NP) {
            rowcnt[i] = 0; rowfirst[i] = 0x7fffffff; rowiter[i] = RI_BIG;
            prior[i] = 0; priorcol[i] = 0;
        }
        if (i < NG) { colsum[i] = 0; done[i] = 0; }
        if (i < 32) scal[i] = 0;
    } else if (b < PB_G0) {
        int i0 = (b - PB_CLS0) * CLS_TI;
        bool full = (i0 + CLS_TI) <= NP;
        if (full) {
            const float* src = logits + (size_t)i0 * NC;
            for (int e = threadIdx.x; e < CLS_TI * NC; e += 256) {
                int di = e / NC, c = e - di * NC;
                sl[di * (NC + 1) + c] = src[e];
            }
        } else {
            for (int e = threadIdx.x; e < CLS_TI * NC; e += 256) {
                int di = e / NC, c = e - di * NC;
                int i = i0 + di;
                sl[di * (NC + 1) + c] = (i < NP) ? logits[(size_t)i * NC + c] : 0.0f;
            }
        }
        __syncthreads();
        for (int e = threadIdx.x; e < CLS_TI * NC; e += 256) {
            int c = e >> 6, di = e & 63;
            int i = i0 + di;
            if (i >= NP) continue;
            float x = sl[di * (NC + 1) + c];
            float p = 1.0f / (1.0f + expf(-x));
            float neg = -log1pf(-(p - 1e-12f)) * 0.75f * (p * p);
            float om = 1.0f - p;
            float pos = -logf(p + 1e-12f) * 0.25f * (om * om);
            clsval[(size_t)c * NP + i] = (pos - neg) * 2.0f;   // * CLS_W
        }
    } else if (b < PB_V0) {
#pragma clang fp contract(off)
        int j = (b - PB_G0) * 256 + threadIdx.x;
        if (j < NG) {
            float fw = (float)imgw[0], fh = (float)imgh[0];
            float4 g = ((const float4*)gb)[j];
            float gcx = (g.x + g.z) * 0.5f, gcy = (g.y + g.w) * 0.5f;
            float gw = g.z - g.x, gh = g.w - g.y;
            float4 cb; cb.x = gcx - 2.5f * gw; cb.y = gcy - 2.5f * gh;
            cb.z = gcx + 2.5f * gw; cb.w = gcy + 2.5f * gh;
            gcb[j] = cb;
            float4 Gn; Gn.x = g.x / fw; Gn.y = g.y / fh; Gn.z = g.z / fw; Gn.w = g.w / fh;
            gnm[j] = Gn;
            gar[j] = (g.z - g.x) * (g.w - g.y);
        }
    } else {
#pragma clang fp contract(off)
        int wave = threadIdx.x >> 6;
        int lane = threadIdx.x & 63;
        int i = (b - PB_V0) * 4 + wave;
        if (i >= NP) return;
        float4 p = ((const float4*)pb)[i];
        float pcx = (p.x + p.z) * 0.5f, pcy = (p.y + p.w) * 0.5f;
        int vb = 0, vc = 0;
        const float4* gb4 = (const float4*)gb;
        for (int j = lane; j < NG; j += 64) {
            float4 g = gb4[j];
            vb |= (pcx > g.x && pcx < g.z && pcy > g.y && pcy < g.w) ? 1 : 0;
            float gcx = (g.x + g.z) * 0.5f, gcy = (g.y + g.w) * 0.5f;
            float gw = g.z - g.x, gh = g.w - g.y;
            vc |= (pcx > gcx - 2.5f * gw && pcx < gcx + 2.5f * gw &&
                   pcy > gcy - 2.5f * gh && pcy < gcy + 2.5f * gh) ? 1 : 0;
        }
        int any = (__any(vb) ? 1 : 0) | (__any(vc) ? 1 : 0);
        if (lane == 0) {
            float fw = (float)imgw[0], fh = (float)imgh[0];
            float4 pn; pn.x = p.x / fw; pn.y = p.y / fh; pn.z = p.z / fw; pn.w = p.w / fh;
            pnorm[i] = pn;
            float4 pi4; pi4.x = pcx; pi4.y = pcy;
            pi4.z = (p.z - p.x) * (p.w - p.y);
            pi4.w = any ? 0.0f : 10000.0f;
            pinfo[i] = pi4;
        }
    }
}

// ---------------------------------------------------------------------------
// k_cost2: block (j, chunk c). Branchless per-thread TOP-2 over constant-trip
// main loop; stride-7 LDS tree merge (runtime indexing in LDS — never in
// registers, cf. R12 scratch-spill); detect + cold exact fallback. Last chunk
// of each gt (device-scope ticket, proven R12) merges both chunks inline:
// top5 store, dk, row atomics — k_costmerge launch eliminated.
// ---------------------------------------------------------------------------
__global__ __launch_bounds__(256) void k_cost2(
        const float* __restrict__ pb, const float* __restrict__ gb,
        const int* __restrict__ glab, const float* __restrict__ clsval,
        const float4* __restrict__ pnorm, const float4* __restrict__ pinfo,
        const float4* __restrict__ gcb, const float4* __restrict__ gnm,
        const float* __restrict__ gar,
        unsigned long long* __restrict__ pck, float* __restrict__ piv,
        int* __restrict__ done,
        int* __restrict__ rowcnt, int* __restrict__ rowfirst,
        int* __restrict__ rowiter, int* __restrict__ top5,
        int* __restrict__ dkarr)
{
    __shared__ unsigned long long s_k[256 * 7];
    __shared__ float s_iv[256 * 7];
    __shared__ int s_bad;

    int j = blockIdx.x >> 1;
    int c = blockIdx.x & 1;
    int tid = threadIdx.x;
    if (tid == 0) s_bad = 0;
    float4 g  = ((const float4*)gb)[j];
    float4 cb = gcb[j];
    float4 Gn = gnm[j];
    float  ga = gar[j];
    const float* clscol = clsval + (size_t)glab[j] * NP;
    const float4* pb4 = (const float4*)pb;
    int base_i = c * CHSZ;

    // ---- main pass: branchless top-2 ----
    unsigned long long k0 = KMAX, k1 = KMAX;
    float i0 = -1.0f, i1 = -1.0f;
#pragma unroll 4
    for (int k = 0; k < MAIN_IT; k++) {
        int i = base_i + tid + k * 256;
        float cc, iou;
        cost_iou(pb4[i], pnorm[i], pinfo[i], g, cb, Gn, ga, clscol[i], cc, iou);
        unsigned long long key = packkey(cc, i);
        unsigned long long mx = (k0 > key) ? k0 : key;
        k0 = (k0 > key) ? key : k0;
        k1 = (k1 > mx) ? mx : k1;
        float mnv = fminf(i0, iou);
        i0 = fmaxf(i0, iou);
        i1 = fmaxf(i1, mnv);
    }
    if (tid < TAIL_N) {
        int i = base_i + MAIN_IT * 256 + tid;
        float cc, iou;
        cost_iou(pb4[i], pnorm[i], pinfo[i], g, cb, Gn, ga, clscol[i], cc, iou);
        unsigned long long key = packkey(cc, i);
        unsigned long long mx = (k0 > key) ? k0 : key;
        k0 = (k0 > key) ? key : k0;
        k1 = (k1 > mx) ? mx : k1;
        float mnv = fminf(i0, iou);
        i0 = fmaxf(i0, iou);
        i1 = fmaxf(i1, mnv);
    }

    int base = tid * 7;
    s_k[base+0] = k0; s_k[base+1] = k1;
    s_k[base+2] = KMAX; s_k[base+3] = KMAX; s_k[base+4] = KMAX; s_k[base+5] = KMAX;
    s_iv[base+0] = i0; s_iv[base+1] = i1;
    s_iv[base+2] = -2.0f; s_iv[base+3] = -2.0f; s_iv[base+4] = -2.0f; s_iv[base+5] = -2.0f;
    __syncthreads();

    for (int w = 128; w > 0; w >>= 1) {
        if (tid < w) {
            int a = tid * 7, bb = (tid + w) * 7;
            unsigned long long ok[5]; float og[5];
            int pa = a, pbp = bb;
#pragma unroll
            for (int t = 0; t < 5; t++) {
                unsigned long long A = s_k[pa], B = s_k[pbp];
                if (A <= B) { ok[t] = A; pa++; } else { ok[t] = B; pbp++; }
            }
            int qa = a, qb = bb;
#pragma unroll
            for (int t = 0; t < 5; t++) {
                float A = s_iv[qa], B = s_iv[qb];
                if (A >= B) { og[t] = A; qa++; } else { og[t] = B; qb++; }
            }
#pragma unroll
            for (int t = 0; t < 5; t++) { s_k[a+t] = ok[t]; s_iv[a+t] = og[t]; }
        }
        __syncthreads();
    }

    // ---- exactness detection ----
    if (k1 < s_k[4] || i1 > s_iv[4]) s_bad = 1;
    __syncthreads();

    if (s_bad) {
        // cold exact path: full per-thread top-5 + same tree merge
        unsigned long long kv[5]; float iv[5];
#pragma unroll
        for (int t = 0; t < 5; t++) { kv[t] = KMAX; iv[t] = -1.0f; }
        for (int k = 0; k <= MAIN_IT; k++) {
            if (k == MAIN_IT && tid >= TAIL_N) break;
            int i = base_i + tid + k * 256;
            float cc, iou;
            cost_iou(pb4[i], pnorm[i], pinfo[i], g, cb, Gn, ga, clscol[i], cc, iou);
            unsigned long long key = packkey(cc, i);
            if (key < kv[4]) {
                kv[4] = key;
#pragma unroll
                for (int t = 4; t > 0; t--)
                    if (kv[t] < kv[t-1]) { unsigned long long tv = kv[t]; kv[t] = kv[t-1]; kv[t-1] = tv; }
            }
            if (iou > iv[4]) {
                iv[4] = iou;
#pragma unroll
                for (int t = 4; t > 0; t--)
                    if (iv[t] > iv[t-1]) { float tv = iv[t]; iv[t] = iv[t-1]; iv[t-1] = tv; }
            }
        }
#pragma unroll
        for (int t = 0; t < 5; t++) { s_k[base+t] = kv[t]; s_iv[base+t] = iv[t]; }
        s_k[base+5] = KMAX; s_iv[base+5] = -2.0f;
        __syncthreads();
        for (int w = 128; w > 0; w >>= 1) {
            if (tid < w) {
                int a = tid * 7, bb = (tid + w) * 7;
                unsigned long long ok[5]; float og[5];
                int pa = a, pbp = bb;
#pragma unroll
                for (int t = 0; t < 5; t++) {
                    unsigned long long A = s_k[pa], B = s_k[pbp];
                    if (A <= B) { ok[t] = A; pa++; } else { ok[t] = B; pbp++; }
                }
                int qa = a, qb = bb;
#pragma unroll
                for (int t = 0; t < 5; t++) {
                    float A = s_iv[qa], B = s_iv[qb];
                    if (A >= B) { og[t] = A; qa++; } else { og[t] = B; qb++; }
                }
#pragma unroll
                for (int t = 0; t < 5; t++) { s_k[a+t] = ok[t]; s_iv[a+t] = og[t]; }
            }
            __syncthreads();
        }
    }

    if (tid == 0) {
        int ob = blockIdx.x * 5;
#pragma unroll
        for (int t = 0; t < 5; t++) { pck[ob + t] = s_k[t]; piv[ob + t] = s_iv[t]; }
        __threadfence();
        int ticket = atomicAdd(&done[j], 1);
        if (ticket == 1) {
            __threadfence();
            int mb = j * 2 * 5;
            int h0 = 0, h1 = 0;
            int besti[5];
#pragma unroll
            for (int r = 0; r < 5; r++) {
                unsigned long long v0 = pck[mb + h0];
                unsigned long long v1 = pck[mb + 5 + h1];
                if (v0 <= v1) { besti[r] = keyidx(v0); h0++; }
                else          { besti[r] = keyidx(v1); h1++; }
            }
            int g0 = 0, g1 = 0;
            float ivm[5];
#pragma unroll
            for (int r = 0; r < 5; r++) {
                float v0 = piv[mb + g0];
                float v1 = piv[mb + 5 + g1];
                if (v0 >= v1) { ivm[r] = v0; g0++; } else { ivm[r] = v1; g1++; }
            }
            float s = (((ivm[0] + ivm[1]) + ivm[2]) + ivm[3]) + ivm[4];
            int dk = (int)s;                 // astype(int32): truncation
            if (dk < 1) dk = 1;
            dkarr[j] = dk;
#pragma unroll
            for (int r = 0; r < 5; r++) top5[j * 5 + r] = besti[r];
            for (int t = 0; t < dk; t++) {
                int r = besti[t];
                atomicAdd(&rowcnt[r], 1);
                atomicMin(&rowfirst[r], j);
                atomicMin(&rowiter[r], -1);   // initially matched
            }
        }
    }
}

// ---------------------------------------------------------------------------
// Fused prior-detect + pfix + surv.
// Blocks [0,2500): rows 4b..4b+3 with rowcnt>1 -> prior=1, EXACT top-8 of the
// row's uninflated cost (per-thread exact sorted <=4-sample list, stride-9
// LDS tree merge) -> ptv/pti (iterC fast path), priorcol=top[0], colsum++.
// Blocks [2500,2504): surviving single-pick rows -> colsum.
// ---------------------------------------------------------------------------
__global__ __launch_bounds__(256) void k_pfixsurv(const float* __restrict__ pb,
        const float* __restrict__ gb, const int* __restrict__ glab,
        const float* __restrict__ clsval,
        const float4* __restrict__ pnorm, const float4* __restrict__ pinfo,
        const float4* __restrict__ gcb, const float4* __restrict__ gnm,
        const float* __restrict__ gar,
        int* __restrict__ prior, int* __restrict__ priorcol,
        int* __restrict__ colsum,
        const int* __restrict__ rowcnt, const int* __restrict__ top5,
        const int* __restrict__ dkarr,
        float* __restrict__ ptv, int* __restrict__ pti)
{
    int b = blockIdx.x;
    int tid = threadIdx.x;
    if (b >= 2500) {
        int j = (b - 2500) * 256 + tid;
        if (j >= NG) return;
        int c = 0;
        int dk = dkarr[j];
        for (int t = 0; t < dk; t++) if (rowcnt[top5[j * 5 + t]] == 1) c++;
        if (c) atomicAdd(&colsum[j], c);
        return;
    }
    __shared__ unsigned long long s_k[256 * 9];
    for (int q = 0; q < 4; q++) {
        int row = b * 4 + q;
        if (rowcnt[row] <= 1) continue;      // uniform across block
        if (tid == 0) prior[row] = 1;
        float4 p = ((const float4*)pb)[row];
        float4 pn = pnorm[row];
        float4 pi4 = pinfo[row];

        // per-thread EXACT sorted top-(<=4) over its <=4 samples
        unsigned long long kv[4] = { KMAX, KMAX, KMAX, KMAX };
        for (int j = tid; j < NG; j += 256) {
            float cc, iou;
            cost_iou(p, pn, pi4, ((const float4*)gb)[j], gcb[j], gnm[j], gar[j],
                     clsval[(size_t)glab[j] * NP + row], cc, iou);
            unsigned long long key = packkey(cc, j);
            if (key < kv[3]) {
                kv[3] = key;
#pragma unroll
                for (int t = 3; t > 0; t--)
                    if (kv[t] < kv[t-1]) { unsigned long long tv = kv[t]; kv[t] = kv[t-1]; kv[t-1] = tv; }
            }
        }
        int base = tid * 9;
#pragma unroll
        for (int t = 0; t < 4; t++) s_k[base + t] = kv[t];
#pragma unroll
        for (int t = 4; t < 9; t++) s_k[base + t] = KMAX;
        __syncthreads();

        // tree merge of sorted 8-lists (slots 0..7, sentinel at 8)
        for (int w = 128; w > 0; w >>= 1) {
            if (tid < w) {
                int a = tid * 9, bb = (tid + w) * 9;
                unsigned long long ok[8];
                int pa = a, pbp = bb;
#pragma unroll
                for (int t = 0; t < 8; t++) {
                    unsigned long long A = s_k[pa], B = s_k[pbp];
                    if (A <= B) { ok[t] = A; pa++; } else { ok[t] = B; pbp++; }
                }
#pragma unroll
                for (int t = 0; t < 8; t++) s_k[a + t] = ok[t];
            }
            __syncthreads();
        }

        if (tid == 0) {
            int nb = keyidx(s_k[0]);         // uninflated argmin (lex)
            priorcol[row] = nb;
            atomicAdd(&colsum[nb], 1);
#pragma unroll
            for (int r = 0; r < 8; r++) {
                ptv[row * 8 + r] = keyval(s_k[r]);
                pti[row * 8 + r] = keyidx(s_k[r]);
            }
        }
        __syncthreads();
    }
}

// ---------------------------------------------------------------------------
// iterB: block per column; active iff colsum[j]==0.
// FAST PATH (proven R13): argmin over uninflated rows = first uninflated
// entry of the column's exact top-5 prefix; full-scan fallback if all 5
// inflated.
// ---------------------------------------------------------------------------
__global__ __launch_bounds__(256) void k_iterB(const float* __restrict__ pb,
        const float* __restrict__ gb, const int* __restrict__ glab,
        const float* __restrict__ clsval,
        const float4* __restrict__ pnorm, const float4* __restrict__ pinfo,
        const float4* __restrict__ gcb, const float4* __restrict__ gnm,
        const float* __restrict__ gar, const int* __restrict__ top5,
        int* __restrict__ rowiter, int* __restrict__ rowcnt,
        int* __restrict__ rowfirst, int* __restrict__ colsum,
        int* __restrict__ scal, int t)
{
    int j = blockIdx.x;
    if (colsum[j] != 0) return;
    int tid = threadIdx.x;
    if (tid == 0) scal[S_BODY + t] = 1;

    __shared__ int s_pos;
    if (tid == 0) {
        int pos = -1;
        for (int r = 0; r < 5; r++) {
            int i = top5[j * 5 + r];
            if (rowiter[i] >= t) { pos = i; break; }
        }
        s_pos = pos;
    }
    __syncthreads();
    int pos = s_pos;

    if (pos < 0) {
        // fallback: full argmin over uninflated rows
        float4 g  = ((const float4*)gb)[j];
        float4 cb = gcb[j];
        float4 Gn = gnm[j];
        float  ga = gar[j];
        const float* clscol = clsval + (size_t)glab[j] * NP;
        const float4* pb4 = (const float4*)pb;
        __shared__ float rv[256]; __shared__ int ri[256];
        float best = FLT_MAX; int bi = 0x7fffffff;
        for (int i = tid; i < NP; i += 256) {
            if (rowiter[i] < t) continue;
            float cc, iou;
            cost_iou(pb4[i], pnorm[i], pinfo[i], g, cb, Gn, ga, clscol[i], cc, iou);
            if (lexless(cc, i, best, bi)) { best = cc; bi = i; }
        }
        rv[tid] = best; ri[tid] = bi; __syncthreads();
        for (int w = 128; w > 0; w >>= 1) {
            if (tid < w) {
                float ov = rv[tid + w]; int oi = ri[tid + w];
                if (lexless(ov, oi, rv[tid], ri[tid])) { rv[tid] = ov; ri[tid] = oi; }
            }
            __syncthreads();
        }
        pos = ri[0];
    }

    if (tid == 0) {
        colsum[j] = 1;
        int old = atomicAdd(&rowcnt[pos], 1);
        if (old >= 1) scal[S_MULTI] = 1;
        atomicMin(&rowfirst[pos], j);
        atomicMin(&rowiter[pos], t);
    }
}

// ---------------------------------------------------------------------------
// iterC (m_fix): iff body ran at t && anymulti. Per prior row (4/block):
// FAST PATH: the post-inflation argmin over the row must lie in the row's
// exact uninflated top-8 unless inflate(v7,k)==winner (outside rows have
// v>=v7, inflation monotone -> can tie but never beat) -> 8 exact-inflation
// probes; block-uniform fallback full scan on tie.
// ---------------------------------------------------------------------------
__global__ __launch_bounds__(256) void k_iterC(const float* __restrict__ pb,
        const float* __restrict__ gb, const int* __restrict__ glab,
        const float* __restrict__ clsval,
        const float4* __restrict__ pnorm, const float4* __restrict__ pinfo,
        const float4* __restrict__ gcb, const float4* __restrict__ gnm,
        const float* __restrict__ gar,
        const int* __restrict__ prior, const int* __restrict__ rowiter,
        const float* __restrict__ ptv, const int* __restrict__ pti,
        int* __restrict__ priorcol, int* __restrict__ colsum,
        int* __restrict__ scal, int t)
{
    if (scal[S_BODY + t] == 0 || scal[S_MULTI] == 0) return;
    int b = blockIdx.x;
    int tid = threadIdx.x;
    __shared__ float rv[256]; __shared__ int ri[256];
    for (int q = 0; q < 4; q++) {
        int row = b * 4 + q;
        if (!prior[row]) continue;           // uniform across block
        int k = t - rowiter[row]; if (k < 0) k = 0;   // prior rows: -1 -> t+1

        // ---- fast path: 8 candidates, exact sequential inflation ----
        float wv = FLT_MAX; int wi = 0x7fffffff;
        float i7 = 0.0f;
#pragma unroll
        for (int r = 0; r < 8; r++) {
            float v = ptv[row * 8 + r];
            int ix = pti[row * 8 + r];
            float iv = inflate(v, k);
            if (lexless(iv, ix, wv, wi)) { wv = iv; wi = ix; }
            if (r == 7) i7 = iv;
        }
        bool safe = (i7 > wv);               // deterministic, block-uniform

        int nb;
        if (safe) {
            nb = wi;
        } else {
            // fallback: cooperative full row scan with exact inflation
            float4 p = ((const float4*)pb)[row];
            float4 pn = pnorm[row];
            float4 pi4 = pinfo[row];
            float best = FLT_MAX; int bj = 0x7fffffff;
            for (int j = tid; j < NG; j += 256) {
                float cc, iou;
                cost_iou(p, pn, pi4, ((const float4*)gb)[j], gcb[j], gnm[j], gar[j],
                         clsval[(size_t)glab[j] * NP + row], cc, iou);
                float val = inflate(cc, k);
                if (lexless(val, j, best, bj)) { best = val; bj = j; }
            }
            rv[tid] = best; ri[tid] = bj; __syncthreads();
            for (int w = 128; w > 0; w >>= 1) {
                if (tid < w) {
                    float ov = rv[tid + w]; int oi = ri[tid + w];
                    if (lexless(ov, oi, rv[tid], ri[tid])) { rv[tid] = ov; ri[tid] = oi; }
                }
                __syncthreads();
            }
            nb = ri[0];
            __syncthreads();
        }

        if (tid == 0) {
            int oldc = priorcol[row];
            if (nb != oldc) {
                atomicSub(&colsum[oldc], 1);
                atomicAdd(&colsum[nb], 1);
                priorcol[row] = nb;
            }
        }
        __syncthreads();
    }
}

// ---------------------------------------------------------------------------
// Final: fg = rowcnt>0; matched = priorcol (prior rows) else rowfirst. int32.
// ---------------------------------------------------------------------------
__global__ __launch_bounds__(256) void k_final(const int* __restrict__ rowcnt,
        const int* __restrict__ prior, const int* __restrict__ priorcol,
        const int* __restrict__ rowfirst, int* __restrict__ out)
{
    int i = blockIdx.x * 256 + threadIdx.x;
    if (i >= NP) return;
    int fg = rowcnt[i] > 0;
    out[i] = fg ? 1 : 0;
    out[NP + i] = fg ? (prior[i] ? priorcol[i] : rowfirst[i]) : 0;
}

extern "C" void kernel_launch(void* const* d_in, const int* in_sizes, int n_in,
                              void* d_out, int out_size, void* d_ws, size_t ws_size,
                              hipStream_t stream)
{
    (void)in_sizes; (void)n_in; (void)out_size; (void)ws_size;
    const float* logits = (const float*)d_in[0];
    const float* pboxes = (const float*)d_in[1];
    const float* gboxes = (const float*)d_in[2];
    const int*   glab   = (const int*)d_in[3];
    const int*   imgh   = (const int*)d_in[4];
    const int*   imgw   = (const int*)d_in[5];
    int* out = (int*)d_out;

    char* w = (char*)d_ws;
    float*  clsval  = (float*)(w);                    // 3,200,000
    float4* pnorm   = (float4*)(w + 3200000);         //   160,000
    float4* pinfo   = (float4*)(w + 3360000);         //   160,000
    float4* gcb     = (float4*)(w + 3520000);         //    16,000
    float4* gnm     = (float4*)(w + 3536000);         //    16,000
    float*  gar     = (float*)(w + 3552000);          //     4,000
    int* rowcnt     = (int*)(w + 3556000);            //    40,000
    int* rowfirst   = (int*)(w + 3596000);            //    40,000
    int* rowiter    = (int*)(w + 3636000);            //    40,000
    int* prior      = (int*)(w + 3676000);            //    40,000
    int* priorcol   = (int*)(w + 3716000);            //    40,000
    int* top5       = (int*)(w + 3756000);            //    20,000
    int* dkarr      = (int*)(w + 3776000);            //     4,000
    int* colsum     = (int*)(w + 3780000);            //     4,000
    int* scal       = (int*)(w + 3784000);            //       128
    unsigned long long* pck = (unsigned long long*)(w + 3784128); // 80,000
    float* piv      = (float*)(w + 3864128);          //    40,000
    int* done       = (int*)(w + 3904128);            //     4,000
    float* ptv      = (float*)(w + 3908128);          //   320,000
    int*   pti      = (int*)(w + 4228128);            //   320,000

    hipLaunchKernelGGL(k_prep, dim3(2701), dim3(256), 0, stream,
                       logits, pboxes, gboxes, imgw, imgh,
                       clsval, pnorm, pinfo, gcb, gnm, gar,
                       rowcnt, rowfirst, rowiter, prior, priorcol, colsum, scal, done);
    hipLaunchKernelGGL(k_cost2, dim3(NG * NCH), dim3(256), 0, stream,
                       pboxes, gboxes, glab, clsval, pnorm, pinfo, gcb, gnm, gar,
                       pck, piv, done, rowcnt, rowfirst, rowiter, top5, dkarr);
    hipLaunchKernelGGL(k_pfixsurv, dim3(2504), dim3(256), 0, stream,
                       pboxes, gboxes, glab, clsval, pnorm, pinfo, gcb, gnm, gar,
                       prior, priorcol, colsum, rowcnt, top5, dkarr, ptv, pti);
    for (int t = 0; t < LMAX; t++) {
        hipLaunchKernelGGL(k_iterB, dim3(NG), dim3(256), 0, stream,
                           pboxes, gboxes, glab, clsval, pnorm, pinfo, gcb, gnm, gar,
                           top5, rowiter, rowcnt, rowfirst, colsum, scal, t);
        hipLaunchKernelGGL(k_iterC, dim3(2500), dim3(256), 0, stream,
                           pboxes, gboxes, glab, clsval, pnorm, pinfo, gcb, gnm, gar,
                           prior, rowiter, ptv, pti, priorcol, colsum, scal, t);
    }
    hipLaunchKernelGGL(k_final, dim3(40), dim3(256), 0, stream,
                       rowcnt, prior, priorcol, rowfirst, out);
}

// Round 15
// 172.105 us; speedup vs baseline: 1.2921x; 1.2921x over previous
//
#include <hip/hip_runtime.h>
#include <cfloat>
#include <cmath>

#define NP 10000
#define NG 1000
#define NC 80
#define LMAX 6
#define NCH 2
#define CHSZ (NP / NCH)
#define MAIN_IT 19          // 19*256 = 4864 uniform indices per 5000-chunk
#define TAIL_N  136         // remaining 136 indices

#define S_MULTI 12
#define S_BODY  16
#define RI_BIG  0x3fffffff
#define KMAX    0xFFFFFFFFFFFFFFFFull

__device__ __forceinline__ bool lexless(float av, int ai, float bv, int bi) {
    return (av < bv) || (av == bv && ai < bi);
}

// float -> order-preserving u32 (no NaNs in this data), packed with index.
// ascending u64 order == lexicographic (value asc, index asc).
__device__ __forceinline__ unsigned long long packkey(float v, int idx) {
    unsigned u = __float_as_uint(v);
    u ^= (unsigned)(((int)u) >> 31) | 0x80000000u;
    return ((unsigned long long)u << 32) | (unsigned)idx;
}
__device__ __forceinline__ int keyidx(unsigned long long k) {
    return (int)(unsigned)(k & 0xFFFFFFFFu);
}
__device__ __forceinline__ float keyval(unsigned long long k) {
    unsigned u = (unsigned)(k >> 32);
    u = (u & 0x80000000u) ? (u ^ 0x80000000u) : ~u;   // inverse transform
    return __uint_as_float(u);
}

// Exact sequential +1e5 inflation (reference adds 1e5 once per loop iter).
__device__ __forceinline__ float inflate(float c, int k) {
    for (int q = 0; q < k; q++) c += 100000.0f;
    return c;
}

// Per-pair cost+iou from precomputed tables. Contraction OFF so every kernel
// that recomputes cost(i,j) agrees bit-exactly.
__device__ __forceinline__ void cost_iou(float4 p, float4 pn, float4 pi,
        float4 g, float4 cb, float4 Gn, float ga, float clsv,
        float& cc_out, float& iou_out) {
#pragma clang fp contract(off)
    float wx = fminf(p.z, g.z) - fmaxf(p.x, g.x); wx = fmaxf(wx, 0.0f);
    float wy = fminf(p.w, g.w) - fmaxf(p.y, g.y); wy = fmaxf(wy, 0.0f);
    float inter = wx * wy;
    float uni = pi.z + ga - inter;
    float iou = inter / fmaxf(uni, 1e-12f);
    float ex = fmaxf(p.z, g.z) - fminf(p.x, g.x); ex = fmaxf(ex, 0.0f);
    float ey = fmaxf(p.w, g.w) - fminf(p.y, g.y); ey = fmaxf(ey, 0.0f);
    float enc = ex * ey;
    float giou = iou - (enc - uni) / fmaxf(enc, 1e-12f);
    float l1 = ((fabsf(pn.x - Gn.x) + fabsf(pn.y - Gn.y))
                + fabsf(pn.z - Gn.z)) + fabsf(pn.w - Gn.w);
    float cc = clsv + l1 * 5.0f;
    cc = cc + (-giou * 2.0f);
    bool inb = (pi.x > g.x && pi.x < g.z && pi.y > g.y && pi.y < g.w);
    bool inc = (pi.x > cb.x && pi.x < cb.z && pi.y > cb.y && pi.y < cb.w);
    cc = cc + ((inb && inc) ? 0.0f : 100.0f);
    cc = cc + pi.w;
    cc_out = cc; iou_out = iou;
}

// ---------------------------------------------------------------------------
// Fused prep. Block ranges:
//  [0,40): init state; [40,197): cls table; [197,201): per-gt tables;
//  [201,2701): wave-per-pred validity + per-pred tables
// ---------------------------------------------------------------------------
#define CLS_TI 64
#define PB_CLS0 40
#define PB_G0   197
#define PB_V0   201
__global__ __launch_bounds__(256) void k_prep(const float* __restrict__ logits,
        const float* __restrict__ pb, const float* __restrict__ gb,
        const int* __restrict__ imgw, const int* __restrict__ imgh,
        float* __restrict__ clsval, float4* __restrict__ pnorm,
        float4* __restrict__ pinfo, float4* __restrict__ gcb,
        float4* __restrict__ gnm, float* __restrict__ gar,
        int* rowcnt, int* rowfirst, int* rowiter, int* prior, int* priorcol,
        int* colsum, int* scal)
{
    __shared__ float sl[CLS_TI * (NC + 1)];
    int b = blockIdx.x;
    if (b < PB_CLS0) {
        int i = b * 256 + threadIdx.x;
        if (i < NP) {
            rowcnt[i] = 0; rowfirst[i] = 0x7fffffff; rowiter[i] = RI_BIG;
            prior[i] = 0; priorcol[i] = 0;
        }
        if (i < NG) colsum[i] = 0;
        if (i < 32) scal[i] = 0;
    } else if (b < PB_G0) {
        int i0 = (b - PB_CLS0) * CLS_TI;
        bool full = (i0 + CLS_TI) <= NP;
        if (full) {
            const float* src = logits + (size_t)i0 * NC;
            for (int e = threadIdx.x; e < CLS_TI * NC; e += 256) {
                int di = e / NC, c = e - di * NC;
                sl[di * (NC + 1) + c] = src[e];
            }
        } else {
            for (int e = threadIdx.x; e < CLS_TI * NC; e += 256) {
                int di = e / NC, c = e - di * NC;
                int i = i0 + di;
                sl[di * (NC + 1) + c] = (i < NP) ? logits[(size_t)i * NC + c] : 0.0f;
            }
        }
        __syncthreads();
        for (int e = threadIdx.x; e < CLS_TI * NC; e += 256) {
            int c = e >> 6, di = e & 63;
            int i = i0 + di;
            if (i >= NP) continue;
            float x = sl[di * (NC + 1) + c];
            float p = 1.0f / (1.0f + expf(-x));
            float neg = -log1pf(-(p - 1e-12f)) * 0.75f * (p * p);
            float om = 1.0f - p;
            float pos = -logf(p + 1e-12f) * 0.25f * (om * om);
            clsval[(size_t)c * NP + i] = (pos - neg) * 2.0f;   // * CLS_W
        }
    } else if (b < PB_V0) {
#pragma clang fp contract(off)
        int j = (b - PB_G0) * 256 + threadIdx.x;
        if (j < NG) {
            float fw = (float)imgw[0], fh = (float)imgh[0];
            float4 g = ((const float4*)gb)[j];
            float gcx = (g.x + g.z) * 0.5f, gcy = (g.y + g.w) * 0.5f;
            float gw = g.z - g.x, gh = g.w - g.y;
            float4 cb; cb.x = gcx - 2.5f * gw; cb.y = gcy - 2.5f * gh;
            cb.z = gcx + 2.5f * gw; cb.w = gcy + 2.5f * gh;
            gcb[j] = cb;
            float4 Gn; Gn.x = g.x / fw; Gn.y = g.y / fh; Gn.z = g.z / fw; Gn.w = g.w / fh;
            gnm[j] = Gn;
            gar[j] = (g.z - g.x) * (g.w - g.y);
        }
    } else {
#pragma clang fp contract(off)
        int wave = threadIdx.x >> 6;
        int lane = threadIdx.x & 63;
        int i = (b - PB_V0) * 4 + wave;
        if (i >= NP) return;
        float4 p = ((const float4*)pb)[i];
        float pcx = (p.x + p.z) * 0.5f, pcy = (p.y + p.w) * 0.5f;
        int vb = 0, vc = 0;
        const float4* gb4 = (const float4*)gb;
        for (int j = lane; j < NG; j += 64) {
            float4 g = gb4[j];
            vb |= (pcx > g.x && pcx < g.z && pcy > g.y && pcy < g.w) ? 1 : 0;
            float gcx = (g.x + g.z) * 0.5f, gcy = (g.y + g.w) * 0.5f;
            float gw = g.z - g.x, gh = g.w - g.y;
            vc |= (pcx > gcx - 2.5f * gw && pcx < gcx + 2.5f * gw &&
                   pcy > gcy - 2.5f * gh && pcy < gcy + 2.5f * gh) ? 1 : 0;
        }
        int any = (__any(vb) ? 1 : 0) | (__any(vc) ? 1 : 0);
        if (lane == 0) {
            float fw = (float)imgw[0], fh = (float)imgh[0];
            float4 pn; pn.x = p.x / fw; pn.y = p.y / fh; pn.z = p.z / fw; pn.w = p.w / fh;
            pnorm[i] = pn;
            float4 pi4; pi4.x = pcx; pi4.y = pcy;
            pi4.z = (p.z - p.x) * (p.w - p.y);
            pi4.w = any ? 0.0f : 10000.0f;
            pinfo[i] = pi4;
        }
    }
}

// ---------------------------------------------------------------------------
// k_cost2 (R13-exact): block (j, chunk c). Branchless per-thread TOP-2 over
// constant-trip main loop; stride-7 LDS tree merge (runtime indexing in LDS —
// never registers, cf. R12; no device fences/tickets, cf. R14 — both lose
// ~55us); detect + cold exact fallback. Bit-exact top-5 per (j, chunk).
// ---------------------------------------------------------------------------
__global__ __launch_bounds__(256) void k_cost2(
        const float* __restrict__ pb, const float* __restrict__ gb,
        const int* __restrict__ glab, const float* __restrict__ clsval,
        const float4* __restrict__ pnorm, const float4* __restrict__ pinfo,
        const float4* __restrict__ gcb, const float4* __restrict__ gnm,
        const float* __restrict__ gar,
        unsigned long long* __restrict__ pck, float* __restrict__ piv)
{
    __shared__ unsigned long long s_k[256 * 7];
    __shared__ float s_iv[256 * 7];
    __shared__ int s_bad;

    int j = blockIdx.x >> 1;
    int c = blockIdx.x & 1;
    int tid = threadIdx.x;
    if (tid == 0) s_bad = 0;
    float4 g  = ((const float4*)gb)[j];
    float4 cb = gcb[j];
    float4 Gn = gnm[j];
    float  ga = gar[j];
    const float* clscol = clsval + (size_t)glab[j] * NP;
    const float4* pb4 = (const float4*)pb;
    int base_i = c * CHSZ;

    // ---- main pass: branchless top-2 ----
    unsigned long long k0 = KMAX, k1 = KMAX;
    float i0 = -1.0f, i1 = -1.0f;
#pragma unroll 4
    for (int k = 0; k < MAIN_IT; k++) {
        int i = base_i + tid + k * 256;
        float cc, iou;
        cost_iou(pb4[i], pnorm[i], pinfo[i], g, cb, Gn, ga, clscol[i], cc, iou);
        unsigned long long key = packkey(cc, i);
        unsigned long long mx = (k0 > key) ? k0 : key;
        k0 = (k0 > key) ? key : k0;
        k1 = (k1 > mx) ? mx : k1;
        float mnv = fminf(i0, iou);
        i0 = fmaxf(i0, iou);
        i1 = fmaxf(i1, mnv);
    }
    if (tid < TAIL_N) {
        int i = base_i + MAIN_IT * 256 + tid;
        float cc, iou;
        cost_iou(pb4[i], pnorm[i], pinfo[i], g, cb, Gn, ga, clscol[i], cc, iou);
        unsigned long long key = packkey(cc, i);
        unsigned long long mx = (k0 > key) ? k0 : key;
        k0 = (k0 > key) ? key : k0;
        k1 = (k1 > mx) ? mx : k1;
        float mnv = fminf(i0, iou);
        i0 = fmaxf(i0, iou);
        i1 = fmaxf(i1, mnv);
    }

    int base = tid * 7;
    s_k[base+0] = k0; s_k[base+1] = k1;
    s_k[base+2] = KMAX; s_k[base+3] = KMAX; s_k[base+4] = KMAX; s_k[base+5] = KMAX;
    s_iv[base+0] = i0; s_iv[base+1] = i1;
    s_iv[base+2] = -2.0f; s_iv[base+3] = -2.0f; s_iv[base+4] = -2.0f; s_iv[base+5] = -2.0f;
    __syncthreads();

    for (int w = 128; w > 0; w >>= 1) {
        if (tid < w) {
            int a = tid * 7, bb = (tid + w) * 7;
            unsigned long long ok[5]; float og[5];
            int pa = a, pbp = bb;
#pragma unroll
            for (int t = 0; t < 5; t++) {
                unsigned long long A = s_k[pa], B = s_k[pbp];
                if (A <= B) { ok[t] = A; pa++; } else { ok[t] = B; pbp++; }
            }
            int qa = a, qb = bb;
#pragma unroll
            for (int t = 0; t < 5; t++) {
                float A = s_iv[qa], B = s_iv[qb];
                if (A >= B) { og[t] = A; qa++; } else { og[t] = B; qb++; }
            }
#pragma unroll
            for (int t = 0; t < 5; t++) { s_k[a+t] = ok[t]; s_iv[a+t] = og[t]; }
        }
        __syncthreads();
    }

    // ---- exactness detection ----
    if (k1 < s_k[4] || i1 > s_iv[4]) s_bad = 1;
    __syncthreads();

    if (s_bad) {
        // cold exact path: full per-thread top-5 + same tree merge
        unsigned long long kv[5]; float iv[5];
#pragma unroll
        for (int t = 0; t < 5; t++) { kv[t] = KMAX; iv[t] = -1.0f; }
        for (int k = 0; k <= MAIN_IT; k++) {
            if (k == MAIN_IT && tid >= TAIL_N) break;
            int i = base_i + tid + k * 256;
            float cc, iou;
            cost_iou(pb4[i], pnorm[i], pinfo[i], g, cb, Gn, ga, clscol[i], cc, iou);
            unsigned long long key = packkey(cc, i);
            if (key < kv[4]) {
                kv[4] = key;
#pragma unroll
                for (int t = 4; t > 0; t--)
                    if (kv[t] < kv[t-1]) { unsigned long long tv = kv[t]; kv[t] = kv[t-1]; kv[t-1] = tv; }
            }
            if (iou > iv[4]) {
                iv[4] = iou;
#pragma unroll
                for (int t = 4; t > 0; t--)
                    if (iv[t] > iv[t-1]) { float tv = iv[t]; iv[t] = iv[t-1]; iv[t-1] = tv; }
            }
        }
#pragma unroll
        for (int t = 0; t < 5; t++) { s_k[base+t] = kv[t]; s_iv[base+t] = iv[t]; }
        s_k[base+5] = KMAX; s_iv[base+5] = -2.0f;
        __syncthreads();
        for (int w = 128; w > 0; w >>= 1) {
            if (tid < w) {
                int a = tid * 7, bb = (tid + w) * 7;
                unsigned long long ok[5]; float og[5];
                int pa = a, pbp = bb;
#pragma unroll
                for (int t = 0; t < 5; t++) {
                    unsigned long long A = s_k[pa], B = s_k[pbp];
                    if (A <= B) { ok[t] = A; pa++; } else { ok[t] = B; pbp++; }
                }
                int qa = a, qb = bb;
#pragma unroll
                for (int t = 0; t < 5; t++) {
                    float A = s_iv[qa], B = s_iv[qb];
                    if (A >= B) { og[t] = A; qa++; } else { og[t] = B; qb++; }
                }
#pragma unroll
                for (int t = 0; t < 5; t++) { s_k[a+t] = ok[t]; s_iv[a+t] = og[t]; }
            }
            __syncthreads();
        }
    }

    if (tid == 0) {
        int ob = blockIdx.x * 5;
#pragma unroll
        for (int t = 0; t < 5; t++) { pck[ob + t] = s_k[t]; piv[ob + t] = s_iv[t]; }
    }
}

// ---------------------------------------------------------------------------
// Merge partials: thread per gt. Exact 2-way merge of sorted 5-lists.
// Stores the FULL merged top-5 indices (top5) for iterB's fast path, dk,
// row atomics. (Separate 4-block launch — cheap; the R14 in-kernel ticket
// fold cost ~55us in device-scope fences.)
// ---------------------------------------------------------------------------
__global__ __launch_bounds__(256) void k_costmerge(
        const unsigned long long* __restrict__ pck, const float* __restrict__ piv,
        int* __restrict__ rowcnt, int* __restrict__ rowfirst,
        int* __restrict__ rowiter, int* __restrict__ top5,
        int* __restrict__ dkarr)
{
    int j = blockIdx.x * 256 + threadIdx.x;
    if (j >= NG) return;
    int base = j * 2 * 5;
    int h0 = 0, h1 = 0;
    int besti[5];
#pragma unroll
    for (int r = 0; r < 5; r++) {
        unsigned long long v0 = pck[base + h0];
        unsigned long long v1 = pck[base + 5 + h1];
        if (v0 <= v1) { besti[r] = keyidx(v0); h0++; }
        else          { besti[r] = keyidx(v1); h1++; }
    }
    int g0 = 0, g1 = 0;
    float ivm[5];
#pragma unroll
    for (int r = 0; r < 5; r++) {
        float v0 = piv[base + g0];
        float v1 = piv[base + 5 + g1];
        if (v0 >= v1) { ivm[r] = v0; g0++; } else { ivm[r] = v1; g1++; }
    }
    float s = (((ivm[0] + ivm[1]) + ivm[2]) + ivm[3]) + ivm[4];
    int dk = (int)s;                 // astype(int32): truncation
    if (dk < 1) dk = 1;
    dkarr[j] = dk;
#pragma unroll
    for (int r = 0; r < 5; r++) top5[j * 5 + r] = besti[r];
    for (int t = 0; t < dk; t++) {
        int r = besti[t];
        atomicAdd(&rowcnt[r], 1);
        atomicMin(&rowfirst[r], j);
        atomicMin(&rowiter[r], -1);   // initially matched
    }
}

// ---------------------------------------------------------------------------
// Fused prior-detect + pfix + surv.
// Blocks [0,2500): rows 4b..4b+3 with rowcnt>1 -> prior=1, EXACT top-8 of the
// row's uninflated cost (per-thread exact sorted <=4-sample list, stride-9
// LDS tree merge) -> ptv/pti (iterC fast path), priorcol=top[0], colsum++.
// Blocks [2500,2504): surviving single-pick rows -> colsum.
// ---------------------------------------------------------------------------
__global__ __launch_bounds__(256) void k_pfixsurv(const float* __restrict__ pb,
        const float* __restrict__ gb, const int* __restrict__ glab,
        const float* __restrict__ clsval,
        const float4* __restrict__ pnorm, const float4* __restrict__ pinfo,
        const float4* __restrict__ gcb, const float4* __restrict__ gnm,
        const float* __restrict__ gar,
        int* __restrict__ prior, int* __restrict__ priorcol,
        int* __restrict__ colsum,
        const int* __restrict__ rowcnt, const int* __restrict__ top5,
        const int* __restrict__ dkarr,
        float* __restrict__ ptv, int* __restrict__ pti)
{
    int b = blockIdx.x;
    int tid = threadIdx.x;
    if (b >= 2500) {
        int j = (b - 2500) * 256 + tid;
        if (j >= NG) return;
        int c = 0;
        int dk = dkarr[j];
        for (int t = 0; t < dk; t++) if (rowcnt[top5[j * 5 + t]] == 1) c++;
        if (c) atomicAdd(&colsum[j], c);
        return;
    }
    __shared__ unsigned long long s_k[256 * 9];
    for (int q = 0; q < 4; q++) {
        int row = b * 4 + q;
        if (rowcnt[row] <= 1) continue;      // uniform across block
        if (tid == 0) prior[row] = 1;
        float4 p = ((const float4*)pb)[row];
        float4 pn = pnorm[row];
        float4 pi4 = pinfo[row];

        // per-thread EXACT sorted top-(<=4) over its <=4 samples
        unsigned long long kv[4] = { KMAX, KMAX, KMAX, KMAX };
        for (int j = tid; j < NG; j += 256) {
            float cc, iou;
            cost_iou(p, pn, pi4, ((const float4*)gb)[j], gcb[j], gnm[j], gar[j],
                     clsval[(size_t)glab[j] * NP + row], cc, iou);
            unsigned long long key = packkey(cc, j);
            if (key < kv[3]) {
                kv[3] = key;
#pragma unroll
                for (int t = 3; t > 0; t--)
                    if (kv[t] < kv[t-1]) { unsigned long long tv = kv[t]; kv[t] = kv[t-1]; kv[t-1] = tv; }
            }
        }
        int base = tid * 9;
#pragma unroll
        for (int t = 0; t < 4; t++) s_k[base + t] = kv[t];
#pragma unroll
        for (int t = 4; t < 9; t++) s_k[base + t] = KMAX;
        __syncthreads();

        // tree merge of sorted 8-lists (slots 0..7, sentinel at 8)
        for (int w = 128; w > 0; w >>= 1) {
            if (tid < w) {
                int a = tid * 9, bb = (tid + w) * 9;
                unsigned long long ok[8];
                int pa = a, pbp = bb;
#pragma unroll
                for (int t = 0; t < 8; t++) {
                    unsigned long long A = s_k[pa], B = s_k[pbp];
                    if (A <= B) { ok[t] = A; pa++; } else { ok[t] = B; pbp++; }
                }
#pragma unroll
                for (int t = 0; t < 8; t++) s_k[a + t] = ok[t];
            }
            __syncthreads();
        }

        if (tid == 0) {
            int nb = keyidx(s_k[0]);         // uninflated argmin (lex)
            priorcol[row] = nb;
            atomicAdd(&colsum[nb], 1);
#pragma unroll
            for (int r = 0; r < 8; r++) {
                ptv[row * 8 + r] = keyval(s_k[r]);
                pti[row * 8 + r] = keyidx(s_k[r]);
            }
        }
        __syncthreads();
    }
}

// ---------------------------------------------------------------------------
// iterB: block per column; active iff colsum[j]==0.
// FAST PATH (proven R13): argmin over uninflated rows = first uninflated
// entry of the column's exact top-5 prefix; full-scan fallback if all 5
// inflated.
// ---------------------------------------------------------------------------
__global__ __launch_bounds__(256) void k_iterB(const float* __restrict__ pb,
        const float* __restrict__ gb, const int* __restrict__ glab,
        const float* __restrict__ clsval,
        const float4* __restrict__ pnorm, const float4* __restrict__ pinfo,
        const float4* __restrict__ gcb, const float4* __restrict__ gnm,
        const float* __restrict__ gar, const int* __restrict__ top5,
        int* __restrict__ rowiter, int* __restrict__ rowcnt,
        int* __restrict__ rowfirst, int* __restrict__ colsum,
        int* __restrict__ scal, int t)
{
    int j = blockIdx.x;
    if (colsum[j] != 0) return;
    int tid = threadIdx.x;
    if (tid == 0) scal[S_BODY + t] = 1;

    __shared__ int s_pos;
    if (tid == 0) {
        int pos = -1;
        for (int r = 0; r < 5; r++) {
            int i = top5[j * 5 + r];
            if (rowiter[i] >= t) { pos = i; break; }
        }
        s_pos = pos;
    }
    __syncthreads();
    int pos = s_pos;

    if (pos < 0) {
        // fallback: full argmin over uninflated rows
        float4 g  = ((const float4*)gb)[j];
        float4 cb = gcb[j];
        float4 Gn = gnm[j];
        float  ga = gar[j];
        const float* clscol = clsval + (size_t)glab[j] * NP;
        const float4* pb4 = (const float4*)pb;
        __shared__ float rv[256]; __shared__ int ri[256];
        float best = FLT_MAX; int bi = 0x7fffffff;
        for (int i = tid; i < NP; i += 256) {
            if (rowiter[i] < t) continue;
            float cc, iou;
            cost_iou(pb4[i], pnorm[i], pinfo[i], g, cb, Gn, ga, clscol[i], cc, iou);
            if (lexless(cc, i, best, bi)) { best = cc; bi = i; }
        }
        rv[tid] = best; ri[tid] = bi; __syncthreads();
        for (int w = 128; w > 0; w >>= 1) {
            if (tid < w) {
                float ov = rv[tid + w]; int oi = ri[tid + w];
                if (lexless(ov, oi, rv[tid], ri[tid])) { rv[tid] = ov; ri[tid] = oi; }
            }
            __syncthreads();
        }
        pos = ri[0];
    }

    if (tid == 0) {
        colsum[j] = 1;
        int old = atomicAdd(&rowcnt[pos], 1);
        if (old >= 1) scal[S_MULTI] = 1;
        atomicMin(&rowfirst[pos], j);
        atomicMin(&rowiter[pos], t);
    }
}

// ---------------------------------------------------------------------------
// iterC (m_fix): iff body ran at t && anymulti. Per prior row (4/block):
// FAST PATH: the post-inflation argmin must lie in the row's exact uninflated
// top-8 unless inflate(v7,k)==winner (outside rows have v>=v7, inflation
// monotone -> can tie but never beat) -> 8 exact-inflation probes;
// block-uniform fallback full scan on tie.
// ---------------------------------------------------------------------------
__global__ __launch_bounds__(256) void k_iterC(const float* __restrict__ pb,
        const float* __restrict__ gb, const int* __restrict__ glab,
        const float* __restrict__ clsval,
        const float4* __restrict__ pnorm, const float4* __restrict__ pinfo,
        const float4* __restrict__ gcb, const float4* __restrict__ gnm,
        const float* __restrict__ gar,
        const int* __restrict__ prior, const int* __restrict__ rowiter,
        const float* __restrict__ ptv, const int* __restrict__ pti,
        int* __restrict__ priorcol, int* __restrict__ colsum,
        int* __restrict__ scal, int t)
{
    if (scal[S_BODY + t] == 0 || scal[S_MULTI] == 0) return;
    int b = blockIdx.x;
    int tid = threadIdx.x;
    __shared__ float rv[256]; __shared__ int ri[256];
    for (int q = 0; q < 4; q++) {
        int row = b * 4 + q;
        if (!prior[row]) continue;           // uniform across block
        int k = t - rowiter[row]; if (k < 0) k = 0;   // prior rows: -1 -> t+1

        // ---- fast path: 8 candidates, exact sequential inflation ----
        float wv = FLT_MAX; int wi = 0x7fffffff;
        float i7 = 0.0f;
#pragma unroll
        for (int r = 0; r < 8; r++) {
            float v = ptv[row * 8 + r];
            int ix = pti[row * 8 + r];
            float iv = inflate(v, k);
            if (lexless(iv, ix, wv, wi)) { wv = iv; wi = ix; }
            if (r == 7) i7 = iv;
        }
        bool safe = (i7 > wv);               // deterministic, block-uniform

        int nb;
        if (safe) {
            nb = wi;
        } else {
            // fallback: cooperative full row scan with exact inflation
            float4 p = ((const float4*)pb)[row];
            float4 pn = pnorm[row];
            float4 pi4 = pinfo[row];
            float best = FLT_MAX; int bj = 0x7fffffff;
            for (int j = tid; j < NG; j += 256) {
                float cc, iou;
                cost_iou(p, pn, pi4, ((const float4*)gb)[j], gcb[j], gnm[j], gar[j],
                         clsval[(size_t)glab[j] * NP + row], cc, iou);
                float val = inflate(cc, k);
                if (lexless(val, j, best, bj)) { best = val; bj = j; }
            }
            rv[tid] = best; ri[tid] = bj; __syncthreads();
            for (int w = 128; w > 0; w >>= 1) {
                if (tid < w) {
                    float ov = rv[tid + w]; int oi = ri[tid + w];
                    if (lexless(ov, oi, rv[tid], ri[tid])) { rv[tid] = ov; ri[tid] = oi; }
                }
                __syncthreads();
            }
            nb = ri[0];
            __syncthreads();
        }

        if (tid == 0) {
            int oldc = priorcol[row];
            if (nb != oldc) {
                atomicSub(&colsum[oldc], 1);
                atomicAdd(&colsum[nb], 1);
                priorcol[row] = nb;
            }
        }
        __syncthreads();
    }
}

// ---------------------------------------------------------------------------
// Final: fg = rowcnt>0; matched = priorcol (prior rows) else rowfirst. int32.
// ---------------------------------------------------------------------------
__global__ __launch_bounds__(256) void k_final(const int* __restrict__ rowcnt,
        const int* __restrict__ prior, const int* __restrict__ priorcol,
        const int* __restrict__ rowfirst, int* __restrict__ out)
{
    int i = blockIdx.x * 256 + threadIdx.x;
    if (i >= NP) return;
    int fg = rowcnt[i] > 0;
    out[i] = fg ? 1 : 0;
    out[NP + i] = fg ? (prior[i] ? priorcol[i] : rowfirst[i]) : 0;
}

extern "C" void kernel_launch(void* const* d_in, const int* in_sizes, int n_in,
                              void* d_out, int out_size, void* d_ws, size_t ws_size,
                              hipStream_t stream)
{
    (void)in_sizes; (void)n_in; (void)out_size; (void)ws_size;
    const float* logits = (const float*)d_in[0];
    const float* pboxes = (const float*)d_in[1];
    const float* gboxes = (const float*)d_in[2];
    const int*   glab   = (const int*)d_in[3];
    const int*   imgh   = (const int*)d_in[4];
    const int*   imgw   = (const int*)d_in[5];
    int* out = (int*)d_out;

    char* w = (char*)d_ws;
    float*  clsval  = (float*)(w);                    // 3,200,000
    float4* pnorm   = (float4*)(w + 3200000);         //   160,000
    float4* pinfo   = (float4*)(w + 3360000);         //   160,000
    float4* gcb     = (float4*)(w + 3520000);         //    16,000
    float4* gnm     = (float4*)(w + 3536000);         //    16,000
    float*  gar     = (float*)(w + 3552000);          //     4,000
    int* rowcnt     = (int*)(w + 3556000);            //    40,000
    int* rowfirst   = (int*)(w + 3596000);            //    40,000
    int* rowiter    = (int*)(w + 3636000);            //    40,000
    int* prior      = (int*)(w + 3676000);            //    40,000
    int* priorcol   = (int*)(w + 3716000);            //    40,000
    int* top5       = (int*)(w + 3756000);            //    20,000
    int* dkarr      = (int*)(w + 3776000);            //     4,000
    int* colsum     = (int*)(w + 3780000);            //     4,000
    int* scal       = (int*)(w + 3784000);            //       128
    unsigned long long* pck = (unsigned long long*)(w + 3784128); // 80,000
    float* piv      = (float*)(w + 3864128);          //    40,000
    float* ptv      = (float*)(w + 3904128);          //   320,000
    int*   pti      = (int*)(w + 4224128);            //   320,000

    hipLaunchKernelGGL(k_prep, dim3(2701), dim3(256), 0, stream,
                       logits, pboxes, gboxes, imgw, imgh,
                       clsval, pnorm, pinfo, gcb, gnm, gar,
                       rowcnt, rowfirst, rowiter, prior, priorcol, colsum, scal);
    hipLaunchKernelGGL(k_cost2, dim3(NG * NCH), dim3(256), 0, stream,
                       pboxes, gboxes, glab, clsval, pnorm, pinfo, gcb, gnm, gar,
                       pck, piv);
    hipLaunchKernelGGL(k_costmerge, dim3(4), dim3(256), 0, stream,
                       pck, piv, rowcnt, rowfirst, rowiter, top5, dkarr);
    hipLaunchKernelGGL(k_pfixsurv, dim3(2504), dim3(256), 0, stream,
                       pboxes, gboxes, glab, clsval, pnorm, pinfo, gcb, gnm, gar,
                       prior, priorcol, colsum, rowcnt, top5, dkarr, ptv, pti);
    for (int t = 0; t < LMAX; t++) {
        hipLaunchKernelGGL(k_iterB, dim3(NG), dim3(256), 0, stream,
                           pboxes, gboxes, glab, clsval, pnorm, pinfo, gcb, gnm, gar,
                           top5, rowiter, rowcnt, rowfirst, colsum, scal, t);
        hipLaunchKernelGGL(k_iterC, dim3(2500), dim3(256), 0, stream,
                           pboxes, gboxes, glab, clsval, pnorm, pinfo, gcb, gnm, gar,
                           prior, rowiter, ptv, pti, priorcol, colsum, scal, t);
    }
    hipLaunchKernelGGL(k_final, dim3(40), dim3(256), 0, stream,
                       rowcnt, prior, priorcol, rowfirst, out);
}

// Round 16
// 164.699 us; speedup vs baseline: 1.3502x; 1.0450x over previous
//
#include <hip/hip_runtime.h>
#include <cfloat>
#include <cmath>

#define NP 10000
#define NG 1000
#define NC 80
#define LMAX 6
#define NCH 2
#define CHSZ (NP / NCH)
#define MAIN_IT 19          // 19*256 = 4864 uniform indices per 5000-chunk
#define TAIL_N  136         // remaining 136 indices

#define S_MULTI 12
#define S_BODY  16
#define RI_BIG  0x3fffffff
#define KMAX    0xFFFFFFFFFFFFFFFFull

__device__ __forceinline__ bool lexless(float av, int ai, float bv, int bi) {
    return (av < bv) || (av == bv && ai < bi);
}

// float -> order-preserving u32 (no NaNs in this data), packed with index.
// ascending u64 order == lexicographic (value asc, index asc).
__device__ __forceinline__ unsigned long long packkey(float v, int idx) {
    unsigned u = __float_as_uint(v);
    u ^= (unsigned)(((int)u) >> 31) | 0x80000000u;
    return ((unsigned long long)u << 32) | (unsigned)idx;
}
__device__ __forceinline__ int keyidx(unsigned long long k) {
    return (int)(unsigned)(k & 0xFFFFFFFFu);
}

// Exact sequential +1e5 inflation (reference adds 1e5 once per loop iter).
__device__ __forceinline__ float inflate(float c, int k) {
    for (int q = 0; q < k; q++) c += 100000.0f;
    return c;
}

// Per-pair cost+iou from precomputed tables. Contraction OFF so every kernel
// that recomputes cost(i,j) agrees bit-exactly.
__device__ __forceinline__ void cost_iou(float4 p, float4 pn, float4 pi,
        float4 g, float4 cb, float4 Gn, float ga, float clsv,
        float& cc_out, float& iou_out) {
#pragma clang fp contract(off)
    float wx = fminf(p.z, g.z) - fmaxf(p.x, g.x); wx = fmaxf(wx, 0.0f);
    float wy = fminf(p.w, g.w) - fmaxf(p.y, g.y); wy = fmaxf(wy, 0.0f);
    float inter = wx * wy;
    float uni = pi.z + ga - inter;
    float iou = inter / fmaxf(uni, 1e-12f);
    float ex = fmaxf(p.z, g.z) - fminf(p.x, g.x); ex = fmaxf(ex, 0.0f);
    float ey = fmaxf(p.w, g.w) - fminf(p.y, g.y); ey = fmaxf(ey, 0.0f);
    float enc = ex * ey;
    float giou = iou - (enc - uni) / fmaxf(enc, 1e-12f);
    float l1 = ((fabsf(pn.x - Gn.x) + fabsf(pn.y - Gn.y))
                + fabsf(pn.z - Gn.z)) + fabsf(pn.w - Gn.w);
    float cc = clsv + l1 * 5.0f;
    cc = cc + (-giou * 2.0f);
    bool inb = (pi.x > g.x && pi.x < g.z && pi.y > g.y && pi.y < g.w);
    bool inc = (pi.x > cb.x && pi.x < cb.z && pi.y > cb.y && pi.y < cb.w);
    cc = cc + ((inb && inc) ? 0.0f : 100.0f);
    cc = cc + pi.w;
    cc_out = cc; iou_out = iou;
}

// ---------------------------------------------------------------------------
// Fused prep. Block ranges:
//  [0,40): init state; [40,197): cls table; [197,201): per-gt tables;
//  [201,2701): wave-per-pred validity + per-pred tables
// ---------------------------------------------------------------------------
#define CLS_TI 64
#define PB_CLS0 40
#define PB_G0   197
#define PB_V0   201
__global__ __launch_bounds__(256) void k_prep(const float* __restrict__ logits,
        const float* __restrict__ pb, const float* __restrict__ gb,
        const int* __restrict__ imgw, const int* __restrict__ imgh,
        float* __restrict__ clsval, float4* __restrict__ pnorm,
        float4* __restrict__ pinfo, float4* __restrict__ gcb,
        float4* __restrict__ gnm, float* __restrict__ gar,
        int* rowcnt, int* rowfirst, int* rowiter, int* prior, int* priorcol,
        int* colsum, int* scal)
{
    __shared__ float sl[CLS_TI * (NC + 1)];
    int b = blockIdx.x;
    if (b < PB_CLS0) {
        int i = b * 256 + threadIdx.x;
        if (i < NP) {
            rowcnt[i] = 0; rowfirst[i] = 0x7fffffff; rowiter[i] = RI_BIG;
            prior[i] = 0; priorcol[i] = 0;
        }
        if (i < NG) colsum[i] = 0;
        if (i < 32) scal[i] = 0;
    } else if (b < PB_G0) {
        int i0 = (b - PB_CLS0) * CLS_TI;
        bool full = (i0 + CLS_TI) <= NP;
        if (full) {
            const float* src = logits + (size_t)i0 * NC;
            for (int e = threadIdx.x; e < CLS_TI * NC; e += 256) {
                int di = e / NC, c = e - di * NC;
                sl[di * (NC + 1) + c] = src[e];
            }
        } else {
            for (int e = threadIdx.x; e < CLS_TI * NC; e += 256) {
                int di = e / NC, c = e - di * NC;
                int i = i0 + di;
                sl[di * (NC + 1) + c] = (i < NP) ? logits[(size_t)i * NC + c] : 0.0f;
            }
        }
        __syncthreads();
        for (int e = threadIdx.x; e < CLS_TI * NC; e += 256) {
            int c = e >> 6, di = e & 63;
            int i = i0 + di;
            if (i >= NP) continue;
            float x = sl[di * (NC + 1) + c];
            float p = 1.0f / (1.0f + expf(-x));
            float neg = -log1pf(-(p - 1e-12f)) * 0.75f * (p * p);
            float om = 1.0f - p;
            float pos = -logf(p + 1e-12f) * 0.25f * (om * om);
            clsval[(size_t)c * NP + i] = (pos - neg) * 2.0f;   // * CLS_W
        }
    } else if (b < PB_V0) {
#pragma clang fp contract(off)
        int j = (b - PB_G0) * 256 + threadIdx.x;
        if (j < NG) {
            float fw = (float)imgw[0], fh = (float)imgh[0];
            float4 g = ((const float4*)gb)[j];
            float gcx = (g.x + g.z) * 0.5f, gcy = (g.y + g.w) * 0.5f;
            float gw = g.z - g.x, gh = g.w - g.y;
            float4 cb; cb.x = gcx - 2.5f * gw; cb.y = gcy - 2.5f * gh;
            cb.z = gcx + 2.5f * gw; cb.w = gcy + 2.5f * gh;
            gcb[j] = cb;
            float4 Gn; Gn.x = g.x / fw; Gn.y = g.y / fh; Gn.z = g.z / fw; Gn.w = g.w / fh;
            gnm[j] = Gn;
            gar[j] = (g.z - g.x) * (g.w - g.y);
        }
    } else {
#pragma clang fp contract(off)
        int wave = threadIdx.x >> 6;
        int lane = threadIdx.x & 63;
        int i = (b - PB_V0) * 4 + wave;
        if (i >= NP) return;
        float4 p = ((const float4*)pb)[i];
        float pcx = (p.x + p.z) * 0.5f, pcy = (p.y + p.w) * 0.5f;
        int vb = 0, vc = 0;
        const float4* gb4 = (const float4*)gb;
        for (int j = lane; j < NG; j += 64) {
            float4 g = gb4[j];
            vb |= (pcx > g.x && pcx < g.z && pcy > g.y && pcy < g.w) ? 1 : 0;
            float gcx = (g.x + g.z) * 0.5f, gcy = (g.y + g.w) * 0.5f;
            float gw = g.z - g.x, gh = g.w - g.y;
            vc |= (pcx > gcx - 2.5f * gw && pcx < gcx + 2.5f * gw &&
                   pcy > gcy - 2.5f * gh && pcy < gcy + 2.5f * gh) ? 1 : 0;
        }
        int any = (__any(vb) ? 1 : 0) | (__any(vc) ? 1 : 0);
        if (lane == 0) {
            float fw = (float)imgw[0], fh = (float)imgh[0];
            float4 pn; pn.x = p.x / fw; pn.y = p.y / fh; pn.z = p.z / fw; pn.w = p.w / fh;
            pnorm[i] = pn;
            float4 pi4; pi4.x = pcx; pi4.y = pcy;
            pi4.z = (p.z - p.x) * (p.w - p.y);
            pi4.w = any ? 0.0f : 10000.0f;
            pinfo[i] = pi4;
        }
    }
}

// branchless top-2 update (named vars only — no register indexing)
__device__ __forceinline__ void upd2(unsigned long long& k0,
        unsigned long long& k1, unsigned long long key) {
    unsigned long long mx = (k0 > key) ? k0 : key;
    k0 = (k0 > key) ? key : k0;
    k1 = (k1 > mx) ? mx : k1;
}
__device__ __forceinline__ void updi2(float& i0, float& i1, float iou) {
    float mnv = fminf(i0, iou);
    i0 = fmaxf(i0, iou);
    i1 = fmaxf(i1, mnv);
}

// ---------------------------------------------------------------------------
// k_cost2: block (j, chunk c). DUAL-ACCUMULATOR branchless per-thread top-2
// (even iters -> A, odd -> B: halves the serial min-chain, doubles load
// pipelining); end-of-loop merge of two sorted pairs -> sorted 4-list into
// the stride-7 LDS tree (slots 0..3 real, 4..5 sentinel; 5-from-merge tree
// unchanged & correct with pads). Detect per accumulator + cold exact
// fallback (proven R10/R13). No register-array indexing (R12), no fences
// (R14). Bit-exact top-5 per (j, chunk).
// ---------------------------------------------------------------------------
__global__ __launch_bounds__(256) void k_cost2(
        const float* __restrict__ pb, const float* __restrict__ gb,
        const int* __restrict__ glab, const float* __restrict__ clsval,
        const float4* __restrict__ pnorm, const float4* __restrict__ pinfo,
        const float4* __restrict__ gcb, const float4* __restrict__ gnm,
        const float* __restrict__ gar,
        unsigned long long* __restrict__ pck, float* __restrict__ piv)
{
    __shared__ unsigned long long s_k[256 * 7];
    __shared__ float s_iv[256 * 7];
    __shared__ int s_bad;

    int j = blockIdx.x >> 1;
    int c = blockIdx.x & 1;
    int tid = threadIdx.x;
    if (tid == 0) s_bad = 0;
    float4 g  = ((const float4*)gb)[j];
    float4 cb = gcb[j];
    float4 Gn = gnm[j];
    float  ga = gar[j];
    const float* clscol = clsval + (size_t)glab[j] * NP;
    const float4* pb4 = (const float4*)pb;
    int base_i = c * CHSZ;

    // ---- main pass: dual branchless top-2 accumulators ----
    unsigned long long k0a = KMAX, k1a = KMAX, k0b = KMAX, k1b = KMAX;
    float i0a = -1.0f, i1a = -1.0f, i0b = -1.0f, i1b = -1.0f;
#pragma unroll 2
    for (int k = 0; k + 1 < MAIN_IT; k += 2) {
        int ia = base_i + tid + k * 256;
        int ib = ia + 256;
        float cca, ioua, ccb, ioub;
        cost_iou(pb4[ia], pnorm[ia], pinfo[ia], g, cb, Gn, ga, clscol[ia], cca, ioua);
        cost_iou(pb4[ib], pnorm[ib], pinfo[ib], g, cb, Gn, ga, clscol[ib], ccb, ioub);
        upd2(k0a, k1a, packkey(cca, ia));
        upd2(k0b, k1b, packkey(ccb, ib));
        updi2(i0a, i1a, ioua);
        updi2(i0b, i1b, ioub);
    }
    {   // last even iteration (k = MAIN_IT-1 = 18) -> A
        int i = base_i + tid + (MAIN_IT - 1) * 256;
        float cc, iou;
        cost_iou(pb4[i], pnorm[i], pinfo[i], g, cb, Gn, ga, clscol[i], cc, iou);
        upd2(k0a, k1a, packkey(cc, i));
        updi2(i0a, i1a, iou);
    }
    if (tid < TAIL_N) {   // tail -> B
        int i = base_i + MAIN_IT * 256 + tid;
        float cc, iou;
        cost_iou(pb4[i], pnorm[i], pinfo[i], g, cb, Gn, ga, clscol[i], cc, iou);
        upd2(k0b, k1b, packkey(cc, i));
        updi2(i0b, i1b, iou);
    }

    // merge two sorted pairs -> sorted 4 (named vars, branchless)
    unsigned long long m0 = (k0a < k0b) ? k0a : k0b;
    unsigned long long x1 = (k0a < k0b) ? k0b : k0a;   // max of firsts
    unsigned long long x2 = (k1a < k1b) ? k1a : k1b;   // min of seconds
    unsigned long long m3 = (k1a < k1b) ? k1b : k1a;
    unsigned long long m1 = (x1 < x2) ? x1 : x2;
    unsigned long long m2 = (x1 < x2) ? x2 : x1;
    float n0 = fmaxf(i0a, i0b);
    float y1 = fminf(i0a, i0b);
    float y2 = fmaxf(i1a, i1b);
    float n3 = fminf(i1a, i1b);
    float n1 = fmaxf(y1, y2);
    float n2 = fminf(y1, y2);

    int base = tid * 7;
    s_k[base+0] = m0; s_k[base+1] = m1; s_k[base+2] = m2; s_k[base+3] = m3;
    s_k[base+4] = KMAX; s_k[base+5] = KMAX;
    s_iv[base+0] = n0; s_iv[base+1] = n1; s_iv[base+2] = n2; s_iv[base+3] = n3;
    s_iv[base+4] = -2.0f; s_iv[base+5] = -2.0f;
    __syncthreads();

    for (int w = 128; w > 0; w >>= 1) {
        if (tid < w) {
            int a = tid * 7, bb = (tid + w) * 7;
            unsigned long long ok[5]; float og[5];
            int pa = a, pbp = bb;
#pragma unroll
            for (int t = 0; t < 5; t++) {
                unsigned long long A = s_k[pa], B = s_k[pbp];
                if (A <= B) { ok[t] = A; pa++; } else { ok[t] = B; pbp++; }
            }
            int qa = a, qb = bb;
#pragma unroll
            for (int t = 0; t < 5; t++) {
                float A = s_iv[qa], B = s_iv[qb];
                if (A >= B) { og[t] = A; qa++; } else { og[t] = B; qb++; }
            }
#pragma unroll
            for (int t = 0; t < 5; t++) { s_k[a+t] = ok[t]; s_iv[a+t] = og[t]; }
        }
        __syncthreads();
    }

    // ---- exactness detection (per accumulator half) ----
    if (k1a < s_k[4] || k1b < s_k[4] || i1a > s_iv[4] || i1b > s_iv[4]) s_bad = 1;
    __syncthreads();

    if (s_bad) {
        // cold exact path: full per-thread top-5 + same tree merge
        unsigned long long kv[5]; float iv[5];
#pragma unroll
        for (int t = 0; t < 5; t++) { kv[t] = KMAX; iv[t] = -1.0f; }
        for (int k = 0; k <= MAIN_IT; k++) {
            if (k == MAIN_IT && tid >= TAIL_N) break;
            int i = base_i + tid + k * 256;
            float cc, iou;
            cost_iou(pb4[i], pnorm[i], pinfo[i], g, cb, Gn, ga, clscol[i], cc, iou);
            unsigned long long key = packkey(cc, i);
            if (key < kv[4]) {
                kv[4] = key;
#pragma unroll
                for (int t = 4; t > 0; t--)
                    if (kv[t] < kv[t-1]) { unsigned long long tv = kv[t]; kv[t] = kv[t-1]; kv[t-1] = tv; }
            }
            if (iou > iv[4]) {
                iv[4] = iou;
#pragma unroll
                for (int t = 4; t > 0; t--)
                    if (iv[t] > iv[t-1]) { float tv = iv[t]; iv[t] = iv[t-1]; iv[t-1] = tv; }
            }
        }
#pragma unroll
        for (int t = 0; t < 5; t++) { s_k[base+t] = kv[t]; s_iv[base+t] = iv[t]; }
        s_k[base+5] = KMAX; s_iv[base+5] = -2.0f;
        __syncthreads();
        for (int w = 128; w > 0; w >>= 1) {
            if (tid < w) {
                int a = tid * 7, bb = (tid + w) * 7;
                unsigned long long ok[5]; float og[5];
                int pa = a, pbp = bb;
#pragma unroll
                for (int t = 0; t < 5; t++) {
                    unsigned long long A = s_k[pa], B = s_k[pbp];
                    if (A <= B) { ok[t] = A; pa++; } else { ok[t] = B; pbp++; }
                }
                int qa = a, qb = bb;
#pragma unroll
                for (int t = 0; t < 5; t++) {
                    float A = s_iv[qa], B = s_iv[qb];
                    if (A >= B) { og[t] = A; qa++; } else { og[t] = B; qb++; }
                }
#pragma unroll
                for (int t = 0; t < 5; t++) { s_k[a+t] = ok[t]; s_iv[a+t] = og[t]; }
            }
            __syncthreads();
        }
    }

    if (tid == 0) {
        int ob = blockIdx.x * 5;
#pragma unroll
        for (int t = 0; t < 5; t++) { pck[ob + t] = s_k[t]; piv[ob + t] = s_iv[t]; }
    }
}

// ---------------------------------------------------------------------------
// Merge partials: thread per gt. Exact 2-way merge of sorted 5-lists.
// Stores FULL merged top-5 indices (top5) for iterB's fast path, dk,
// row atomics.
// ---------------------------------------------------------------------------
__global__ __launch_bounds__(256) void k_costmerge(
        const unsigned long long* __restrict__ pck, const float* __restrict__ piv,
        int* __restrict__ rowcnt, int* __restrict__ rowfirst,
        int* __restrict__ rowiter, int* __restrict__ top5,
        int* __restrict__ dkarr)
{
    int j = blockIdx.x * 256 + threadIdx.x;
    if (j >= NG) return;
    int base = j * 2 * 5;
    int h0 = 0, h1 = 0;
    int besti[5];
#pragma unroll
    for (int r = 0; r < 5; r++) {
        unsigned long long v0 = pck[base + h0];
        unsigned long long v1 = pck[base + 5 + h1];
        if (v0 <= v1) { besti[r] = keyidx(v0); h0++; }
        else          { besti[r] = keyidx(v1); h1++; }
    }
    int g0 = 0, g1 = 0;
    float ivm[5];
#pragma unroll
    for (int r = 0; r < 5; r++) {
        float v0 = piv[base + g0];
        float v1 = piv[base + 5 + g1];
        if (v0 >= v1) { ivm[r] = v0; g0++; } else { ivm[r] = v1; g1++; }
    }
    float s = (((ivm[0] + ivm[1]) + ivm[2]) + ivm[3]) + ivm[4];
    int dk = (int)s;                 // astype(int32): truncation
    if (dk < 1) dk = 1;
    dkarr[j] = dk;
#pragma unroll
    for (int r = 0; r < 5; r++) top5[j * 5 + r] = besti[r];
    for (int t = 0; t < dk; t++) {
        int r = besti[t];
        atomicAdd(&rowcnt[r], 1);
        atomicMin(&rowfirst[r], j);
        atomicMin(&rowiter[r], -1);   // initially matched
    }
}

// ---------------------------------------------------------------------------
// Fused prior-detect + pfix + surv (R13-plain).
// Blocks [0,2500): rows 4b..4b+3; rows with rowcnt>1 -> prior=1 and
// cooperative argmin over 1000 gts -> priorcol, colsum++.
// Blocks [2500,2504): surviving single-pick rows -> colsum.
// ---------------------------------------------------------------------------
__global__ __launch_bounds__(256) void k_pfixsurv(const float* __restrict__ pb,
        const float* __restrict__ gb, const int* __restrict__ glab,
        const float* __restrict__ clsval,
        const float4* __restrict__ pnorm, const float4* __restrict__ pinfo,
        const float4* __restrict__ gcb, const float4* __restrict__ gnm,
        const float* __restrict__ gar,
        int* __restrict__ prior, int* __restrict__ priorcol,
        int* __restrict__ colsum,
        const int* __restrict__ rowcnt, const int* __restrict__ top5,
        const int* __restrict__ dkarr)
{
    int b = blockIdx.x;
    int tid = threadIdx.x;
    if (b >= 2500) {
        int j = (b - 2500) * 256 + tid;
        if (j >= NG) return;
        int c = 0;
        int dk = dkarr[j];
        for (int t = 0; t < dk; t++) if (rowcnt[top5[j * 5 + t]] == 1) c++;
        if (c) atomicAdd(&colsum[j], c);
        return;
    }
    __shared__ float rv[256]; __shared__ int ri[256];
    for (int q = 0; q < 4; q++) {
        int row = b * 4 + q;
        if (rowcnt[row] <= 1) continue;      // uniform across block
        if (tid == 0) prior[row] = 1;
        float4 p = ((const float4*)pb)[row];
        float4 pn = pnorm[row];
        float4 pi4 = pinfo[row];
        float best = FLT_MAX; int bj = 0x7fffffff;
        for (int j = tid; j < NG; j += 256) {
            float cc, iou;
            cost_iou(p, pn, pi4, ((const float4*)gb)[j], gcb[j], gnm[j], gar[j],
                     clsval[(size_t)glab[j] * NP + row], cc, iou);
            if (lexless(cc, j, best, bj)) { best = cc; bj = j; }
        }
        rv[tid] = best; ri[tid] = bj; __syncthreads();
        for (int w = 128; w > 0; w >>= 1) {
            if (tid < w) {
                float ov = rv[tid + w]; int oi = ri[tid + w];
                if (lexless(ov, oi, rv[tid], ri[tid])) { rv[tid] = ov; ri[tid] = oi; }
            }
            __syncthreads();
        }
        if (tid == 0) {
            priorcol[row] = ri[0];
            atomicAdd(&colsum[ri[0]], 1);
        }
        __syncthreads();
    }
}

// ---------------------------------------------------------------------------
// iterB: block per column; active iff colsum[j]==0.
// FAST PATH (proven R13): argmin over uninflated rows = first uninflated
// entry of the column's exact top-5 prefix; full-scan fallback if all 5
// inflated.
// ---------------------------------------------------------------------------
__global__ __launch_bounds__(256) void k_iterB(const float* __restrict__ pb,
        const float* __restrict__ gb, const int* __restrict__ glab,
        const float* __restrict__ clsval,
        const float4* __restrict__ pnorm, const float4* __restrict__ pinfo,
        const float4* __restrict__ gcb, const float4* __restrict__ gnm,
        const float* __restrict__ gar, const int* __restrict__ top5,
        int* __restrict__ rowiter, int* __restrict__ rowcnt,
        int* __restrict__ rowfirst, int* __restrict__ colsum,
        int* __restrict__ scal, int t)
{
    int j = blockIdx.x;
    if (colsum[j] != 0) return;
    int tid = threadIdx.x;
    if (tid == 0) scal[S_BODY + t] = 1;

    __shared__ int s_pos;
    if (tid == 0) {
        int pos = -1;
        for (int r = 0; r < 5; r++) {
            int i = top5[j * 5 + r];
            if (rowiter[i] >= t) { pos = i; break; }
        }
        s_pos = pos;
    }
    __syncthreads();
    int pos = s_pos;

    if (pos < 0) {
        // fallback: full argmin over uninflated rows
        float4 g  = ((const float4*)gb)[j];
        float4 cb = gcb[j];
        float4 Gn = gnm[j];
        float  ga = gar[j];
        const float* clscol = clsval + (size_t)glab[j] * NP;
        const float4* pb4 = (const float4*)pb;
        __shared__ float rv[256]; __shared__ int ri[256];
        float best = FLT_MAX; int bi = 0x7fffffff;
        for (int i = tid; i < NP; i += 256) {
            if (rowiter[i] < t) continue;
            float cc, iou;
            cost_iou(pb4[i], pnorm[i], pinfo[i], g, cb, Gn, ga, clscol[i], cc, iou);
            if (lexless(cc, i, best, bi)) { best = cc; bi = i; }
        }
        rv[tid] = best; ri[tid] = bi; __syncthreads();
        for (int w = 128; w > 0; w >>= 1) {
            if (tid < w) {
                float ov = rv[tid + w]; int oi = ri[tid + w];
                if (lexless(ov, oi, rv[tid], ri[tid])) { rv[tid] = ov; ri[tid] = oi; }
            }
            __syncthreads();
        }
        pos = ri[0];
    }

    if (tid == 0) {
        colsum[j] = 1;
        int old = atomicAdd(&rowcnt[pos], 1);
        if (old >= 1) scal[S_MULTI] = 1;
        atomicMin(&rowfirst[pos], j);
        atomicMin(&rowiter[pos], t);
    }
}

// ---------------------------------------------------------------------------
// iterC (m_fix, R13-plain): iff body ran at t && anymulti: prior rows
// (4 rows/block) re-argmin their inflated cost (exact sequential +1e5).
// ---------------------------------------------------------------------------
__global__ __launch_bounds__(256) void k_iterC(const float* __restrict__ pb,
        const float* __restrict__ gb, const int* __restrict__ glab,
        const float* __restrict__ clsval,
        const float4* __restrict__ pnorm, const float4* __restrict__ pinfo,
        const float4* __restrict__ gcb, const float4* __restrict__ gnm,
        const float* __restrict__ gar,
        const int* __restrict__ prior, const int* __restrict__ rowiter,
        int* __restrict__ priorcol, int* __restrict__ colsum,
        int* __restrict__ scal, int t)
{
    if (scal[S_BODY + t] == 0 || scal[S_MULTI] == 0) return;
    int b = blockIdx.x;
    int tid = threadIdx.x;
    __shared__ float rv[256]; __shared__ int ri[256];
    for (int q = 0; q < 4; q++) {
        int row = b * 4 + q;
        if (!prior[row]) continue;           // uniform across block
        int k = t - rowiter[row]; if (k < 0) k = 0;   // prior rows: -1 -> t+1
        float4 p = ((const float4*)pb)[row];
        float4 pn = pnorm[row];
        float4 pi4 = pinfo[row];
        float best = FLT_MAX; int bj = 0x7fffffff;
        for (int j = tid; j < NG; j += 256) {
            float cc, iou;
            cost_iou(p, pn, pi4, ((const float4*)gb)[j], gcb[j], gnm[j], gar[j],
                     clsval[(size_t)glab[j] * NP + row], cc, iou);
            float val = inflate(cc, k);
            if (lexless(val, j, best, bj)) { best = val; bj = j; }
        }
        rv[tid] = best; ri[tid] = bj; __syncthreads();
        for (int w = 128; w > 0; w >>= 1) {
            if (tid < w) {
                float ov = rv[tid + w]; int oi = ri[tid + w];
                if (lexless(ov, oi, rv[tid], ri[tid])) { rv[tid] = ov; ri[tid] = oi; }
            }
            __syncthreads();
        }
        if (tid == 0) {
            int nb = ri[0];
            int oldc = priorcol[row];
            if (nb != oldc) {
                atomicSub(&colsum[oldc], 1);
                atomicAdd(&colsum[nb], 1);
                priorcol[row] = nb;
            }
        }
        __syncthreads();
    }
}

// ---------------------------------------------------------------------------
// Final: fg = rowcnt>0; matched = priorcol (prior rows) else rowfirst. int32.
// ---------------------------------------------------------------------------
__global__ __launch_bounds__(256) void k_final(const int* __restrict__ rowcnt,
        const int* __restrict__ prior, const int* __restrict__ priorcol,
        const int* __restrict__ rowfirst, int* __restrict__ out)
{
    int i = blockIdx.x * 256 + threadIdx.x;
    if (i >= NP) return;
    int fg = rowcnt[i] > 0;
    out[i] = fg ? 1 : 0;
    out[NP + i] = fg ? (prior[i] ? priorcol[i] : rowfirst[i]) : 0;
}

extern "C" void kernel_launch(void* const* d_in, const int* in_sizes, int n_in,
                              void* d_out, int out_size, void* d_ws, size_t ws_size,
                              hipStream_t stream)
{
    (void)in_sizes; (void)n_in; (void)out_size; (void)ws_size;
    const float* logits = (const float*)d_in[0];
    const float* pboxes = (const float*)d_in[1];
    const float* gboxes = (const float*)d_in[2];
    const int*   glab   = (const int*)d_in[3];
    const int*   imgh   = (const int*)d_in[4];
    const int*   imgw   = (const int*)d_in[5];
    int* out = (int*)d_out;

    char* w = (char*)d_ws;
    float*  clsval  = (float*)(w);                    // 3,200,000
    float4* pnorm   = (float4*)(w + 3200000);         //   160,000
    float4* pinfo   = (float4*)(w + 3360000);         //   160,000
    float4* gcb     = (float4*)(w + 3520000);         //    16,000
    float4* gnm     = (float4*)(w + 3536000);         //    16,000
    float*  gar     = (float*)(w + 3552000);          //     4,000
    int* rowcnt     = (int*)(w + 3556000);            //    40,000
    int* rowfirst   = (int*)(w + 3596000);            //    40,000
    int* rowiter    = (int*)(w + 3636000);            //    40,000
    int* prior      = (int*)(w + 3676000);            //    40,000
    int* priorcol   = (int*)(w + 3716000);            //    40,000
    int* top5       = (int*)(w + 3756000);            //    20,000
    int* dkarr      = (int*)(w + 3776000);            //     4,000
    int* colsum     = (int*)(w + 3780000);            //     4,000
    int* scal       = (int*)(w + 3784000);            //       128
    unsigned long long* pck = (unsigned long long*)(w + 3784128); // 80,000
    float* piv      = (float*)(w + 3864128);          //    40,000

    hipLaunchKernelGGL(k_prep, dim3(2701), dim3(256), 0, stream,
                       logits, pboxes, gboxes, imgw, imgh,
                       clsval, pnorm, pinfo, gcb, gnm, gar,
                       rowcnt, rowfirst, rowiter, prior, priorcol, colsum, scal);
    hipLaunchKernelGGL(k_cost2, dim3(NG * NCH), dim3(256), 0, stream,
                       pboxes, gboxes, glab, clsval, pnorm, pinfo, gcb, gnm, gar,
                       pck, piv);
    hipLaunchKernelGGL(k_costmerge, dim3(4), dim3(256), 0, stream,
                       pck, piv, rowcnt, rowfirst, rowiter, top5, dkarr);
    hipLaunchKernelGGL(k_pfixsurv, dim3(2504), dim3(256), 0, stream,
                       pboxes, gboxes, glab, clsval, pnorm, pinfo, gcb, gnm, gar,
                       prior, priorcol, colsum, rowcnt, top5, dkarr);
    for (int t = 0; t < LMAX; t++) {
        hipLaunchKernelGGL(k_iterB, dim3(NG), dim3(256), 0, stream,
                           pboxes, gboxes, glab, clsval, pnorm, pinfo, gcb, gnm, gar,
                           top5, rowiter, rowcnt, rowfirst, colsum, scal, t);
        hipLaunchKernelGGL(k_iterC, dim3(2500), dim3(256), 0, stream,
                           pboxes, gboxes, glab, clsval, pnorm, pinfo, gcb, gnm, gar,
                           prior, rowiter, priorcol, colsum, scal, t);
    }
    hipLaunchKernelGGL(k_final, dim3(40), dim3(256), 0, stream,
                       rowcnt, prior, priorcol, rowfirst, out);
}